// Round 1
// baseline (2594.645 us; speedup 1.0000x reference)
//
#include <hip/hip_runtime.h>
#include <math.h>

namespace {

constexpr int kDim   = 1152;
constexpr int kHeads = 9;
constexpr int kHd    = 128;
constexpr int kMid   = 256;
constexpr int kB     = 8;
constexpr int kN     = 1024;
constexpr int kM     = kB * kN;  // 8192 tokens
constexpr float kScale = 0.08838834764831845f;  // 128^-0.5

// C[m,n] (+)= act(sum_k A[m,k]*B[n,k] + bias[n])
// A: [M,K] row-major. Bw: [N,K] row-major (torch Linear weight). 128x128 tile, BK=32.
template<bool TANH, bool ACCUM, bool BIAS>
__global__ __launch_bounds__(256)
void gemm_xwt(const float* __restrict__ A, const float* __restrict__ Bw,
              const float* __restrict__ bias, float* __restrict__ C,
              int K, int ldc, const int* __restrict__ taskp, int mintask)
{
    if (taskp != nullptr && *taskp < mintask) return;

    __shared__ float As[32][128];  // [k][m]
    __shared__ float Bs[32][128];  // [k][n]

    const int bm  = blockIdx.x * 128;
    const int bn  = blockIdx.y * 128;
    const int tid = threadIdx.x;
    const int tx4 = (tid & 15) * 4;   // column micro-offset
    const int ty4 = (tid >> 4) * 4;   // row micro-offset

    float acc[8][8];
#pragma unroll
    for (int i = 0; i < 8; ++i)
#pragma unroll
        for (int j = 0; j < 8; ++j) acc[i][j] = 0.f;

    const int lrow = tid >> 1;          // 0..127
    const int lk   = (tid & 1) * 16;    // 0 or 16
    const float* Ap = A  + (size_t)(bm + lrow) * K + lk;
    const float* Bp = Bw + (size_t)(bn + lrow) * K + lk;

    for (int k0 = 0; k0 < K; k0 += 32) {
#pragma unroll
        for (int c = 0; c < 16; c += 4) {
            const float4 av = *reinterpret_cast<const float4*>(Ap + k0 + c);
            const float4 bv = *reinterpret_cast<const float4*>(Bp + k0 + c);
            As[lk + c + 0][lrow] = av.x;
            As[lk + c + 1][lrow] = av.y;
            As[lk + c + 2][lrow] = av.z;
            As[lk + c + 3][lrow] = av.w;
            Bs[lk + c + 0][lrow] = bv.x;
            Bs[lk + c + 1][lrow] = bv.y;
            Bs[lk + c + 2][lrow] = bv.z;
            Bs[lk + c + 3][lrow] = bv.w;
        }
        __syncthreads();
#pragma unroll 4
        for (int kk = 0; kk < 32; ++kk) {
            const float4 a0 = *reinterpret_cast<const float4*>(&As[kk][ty4]);
            const float4 a1 = *reinterpret_cast<const float4*>(&As[kk][64 + ty4]);
            const float4 b0 = *reinterpret_cast<const float4*>(&Bs[kk][tx4]);
            const float4 b1 = *reinterpret_cast<const float4*>(&Bs[kk][64 + tx4]);
            const float ar[8] = {a0.x, a0.y, a0.z, a0.w, a1.x, a1.y, a1.z, a1.w};
            const float br[8] = {b0.x, b0.y, b0.z, b0.w, b1.x, b1.y, b1.z, b1.w};
#pragma unroll
            for (int i = 0; i < 8; ++i)
#pragma unroll
                for (int j = 0; j < 8; ++j)
                    acc[i][j] = fmaf(ar[i], br[j], acc[i][j]);
        }
        __syncthreads();
    }

#pragma unroll
    for (int i = 0; i < 8; ++i) {
        const int row = bm + ((i < 4) ? (ty4 + i) : (64 + ty4 + i - 4));
        float* cp = C + (size_t)row * ldc + bn;
#pragma unroll
        for (int half = 0; half < 2; ++half) {
            const int colb = half * 64 + tx4;
            float4 v;
            v.x = acc[i][half * 4 + 0];
            v.y = acc[i][half * 4 + 1];
            v.z = acc[i][half * 4 + 2];
            v.w = acc[i][half * 4 + 3];
            if constexpr (BIAS) {
                const float4 bb = *reinterpret_cast<const float4*>(&bias[bn + colb]);
                v.x += bb.x; v.y += bb.y; v.z += bb.z; v.w += bb.w;
            }
            if constexpr (TANH) {
                v.x = tanhf(v.x); v.y = tanhf(v.y);
                v.z = tanhf(v.z); v.w = tanhf(v.w);
            }
            if constexpr (ACCUM) {
                const float4 ov = *reinterpret_cast<const float4*>(cp + colb);
                v.x += ov.x; v.y += ov.y; v.z += ov.z; v.w += ov.w;
            }
            *reinterpret_cast<float4*>(cp + colb) = v;
        }
    }
}

// Flash-style fp32 attention. One block = one (b,h) and a 64-query tile.
// qkv: [8192][3456]; out: [8192][1152] (b,n,h*128+d)
__global__ __launch_bounds__(256)
void attn_fwd(const float* __restrict__ qkv, float* __restrict__ out)
{
    extern __shared__ float smem[];
    float* Qs = smem;              // [128 d][64 q], pre-scaled
    float* Ks = Qs + 128 * 64;     // [128 d][64 k]
    float* Vs = Ks + 128 * 64;     // [64 k][128 d]
    float* Ps = Vs + 64 * 128;     // [64 q][64 k]

    const int bh = blockIdx.y;
    const int b  = bh / kHeads;
    const int h  = bh - b * kHeads;
    const int q0 = blockIdx.x * 64;
    const int tid = threadIdx.x;
    const int tx4 = (tid & 15) * 4;
    const int ty4 = (tid >> 4) * 4;

    const size_t rowstride = 3 * kDim;
    const float* basep = qkv + (size_t)b * kN * rowstride;

    {   // Q tile load (scaled), transposed to d-major
        const int r  = tid >> 2;          // 0..63
        const int dc = (tid & 3) * 32;    // 0,32,64,96
        const float* src = basep + (size_t)(q0 + r) * rowstride + h * kHd + dc;
#pragma unroll
        for (int c = 0; c < 32; c += 4) {
            const float4 v = *reinterpret_cast<const float4*>(src + c);
            Qs[(dc + c + 0) * 64 + r] = v.x * kScale;
            Qs[(dc + c + 1) * 64 + r] = v.y * kScale;
            Qs[(dc + c + 2) * 64 + r] = v.z * kScale;
            Qs[(dc + c + 3) * 64 + r] = v.w * kScale;
        }
    }

    float m_i[4], l_i[4], O[4][8];
#pragma unroll
    for (int i = 0; i < 4; ++i) {
        m_i[i] = -INFINITY; l_i[i] = 0.f;
#pragma unroll
        for (int j = 0; j < 8; ++j) O[i][j] = 0.f;
    }

    for (int kt = 0; kt < kN; kt += 64) {
        __syncthreads();  // previous tile's Ps/Vs/Ks readers done (also fences Q load, iter 0)
        {   // K (transposed) and V (row-major) tile loads
            const int r  = tid >> 2;
            const int dc = (tid & 3) * 32;
            const float* ksrc = basep + (size_t)(kt + r) * rowstride + kDim     + h * kHd + dc;
            const float* vsrc = basep + (size_t)(kt + r) * rowstride + 2 * kDim + h * kHd + dc;
#pragma unroll
            for (int c = 0; c < 32; c += 4) {
                const float4 kv = *reinterpret_cast<const float4*>(ksrc + c);
                Ks[(dc + c + 0) * 64 + r] = kv.x;
                Ks[(dc + c + 1) * 64 + r] = kv.y;
                Ks[(dc + c + 2) * 64 + r] = kv.z;
                Ks[(dc + c + 3) * 64 + r] = kv.w;
                *reinterpret_cast<float4*>(&Vs[r * 128 + dc + c]) =
                    *reinterpret_cast<const float4*>(vsrc + c);
            }
        }
        __syncthreads();

        // S tile: 4x4 scores per thread
        float acc[4][4];
#pragma unroll
        for (int i = 0; i < 4; ++i)
#pragma unroll
            for (int j = 0; j < 4; ++j) acc[i][j] = 0.f;
#pragma unroll 4
        for (int d = 0; d < 128; ++d) {
            const float4 qa = *reinterpret_cast<const float4*>(&Qs[d * 64 + ty4]);
            const float4 kb = *reinterpret_cast<const float4*>(&Ks[d * 64 + tx4]);
            const float qr[4] = {qa.x, qa.y, qa.z, qa.w};
            const float kr[4] = {kb.x, kb.y, kb.z, kb.w};
#pragma unroll
            for (int i = 0; i < 4; ++i)
#pragma unroll
                for (int j = 0; j < 4; ++j)
                    acc[i][j] = fmaf(qr[i], kr[j], acc[i][j]);
        }

        // online softmax (rows = ty4+i, reduce across the 16 tx lanes)
        float mnew[4];
#pragma unroll
        for (int i = 0; i < 4; ++i)
            mnew[i] = fmaxf(fmaxf(acc[i][0], acc[i][1]), fmaxf(acc[i][2], acc[i][3]));
#pragma unroll
        for (int off = 1; off < 16; off <<= 1)
#pragma unroll
            for (int i = 0; i < 4; ++i)
                mnew[i] = fmaxf(mnew[i], __shfl_xor(mnew[i], off));

        float sf[4], rs[4], p[4][4];
#pragma unroll
        for (int i = 0; i < 4; ++i) {
            const float mi = fmaxf(m_i[i], mnew[i]);
            sf[i] = __expf(m_i[i] - mi);   // first tile: exp(-inf) = 0
            float s = 0.f;
#pragma unroll
            for (int j = 0; j < 4; ++j) {
                p[i][j] = __expf(acc[i][j] - mi);
                s += p[i][j];
            }
            rs[i] = s;
            m_i[i] = mi;
        }
#pragma unroll
        for (int off = 1; off < 16; off <<= 1)
#pragma unroll
            for (int i = 0; i < 4; ++i)
                rs[i] += __shfl_xor(rs[i], off);
#pragma unroll
        for (int i = 0; i < 4; ++i) {
            l_i[i] = fmaf(l_i[i], sf[i], rs[i]);
#pragma unroll
            for (int j = 0; j < 8; ++j) O[i][j] *= sf[i];
        }

#pragma unroll
        for (int i = 0; i < 4; ++i)
#pragma unroll
            for (int j = 0; j < 4; ++j)
                Ps[(ty4 + i) * 64 + tx4 + j] = p[i][j];
        __syncthreads();

        // PV: O[i][*] += sum_k P[row][k] * V[k][dcol]
#pragma unroll 4
        for (int k = 0; k < 64; ++k) {
            const float4 v0 = *reinterpret_cast<const float4*>(&Vs[k * 128 + tx4]);
            const float4 v1 = *reinterpret_cast<const float4*>(&Vs[k * 128 + 64 + tx4]);
#pragma unroll
            for (int i = 0; i < 4; ++i) {
                const float pk = Ps[(ty4 + i) * 64 + k];
                O[i][0] = fmaf(pk, v0.x, O[i][0]);
                O[i][1] = fmaf(pk, v0.y, O[i][1]);
                O[i][2] = fmaf(pk, v0.z, O[i][2]);
                O[i][3] = fmaf(pk, v0.w, O[i][3]);
                O[i][4] = fmaf(pk, v1.x, O[i][4]);
                O[i][5] = fmaf(pk, v1.y, O[i][5]);
                O[i][6] = fmaf(pk, v1.z, O[i][6]);
                O[i][7] = fmaf(pk, v1.w, O[i][7]);
            }
        }
    }

#pragma unroll
    for (int i = 0; i < 4; ++i) {
        const float inv = 1.f / l_i[i];
        const int q = q0 + ty4 + i;
        float* dst = out + (size_t)(b * kN + q) * kDim + h * kHd;
        float4 o0, o1;
        o0.x = O[i][0] * inv; o0.y = O[i][1] * inv;
        o0.z = O[i][2] * inv; o0.w = O[i][3] * inv;
        o1.x = O[i][4] * inv; o1.y = O[i][5] * inv;
        o1.z = O[i][6] * inv; o1.w = O[i][7] * inv;
        *reinterpret_cast<float4*>(dst + tx4)      = o0;
        *reinterpret_cast<float4*>(dst + 64 + tx4) = o1;
    }
}

}  // namespace

extern "C" void kernel_launch(void* const* d_in, const int* in_sizes, int n_in,
                              void* d_out, int out_size, void* d_ws, size_t ws_size,
                              hipStream_t stream)
{
    const float* x       = (const float*)d_in[0];
    const float* Wqkv    = (const float*)d_in[1];
    const float* Wproj   = (const float*)d_in[2];
    const float* bproj   = (const float*)d_in[3];
    const float* down_w  = (const float*)d_in[4];
    const float* down_b  = (const float*)d_in[5];
    const float* up_w    = (const float*)d_in[6];
    const float* up_b    = (const float*)d_in[7];
    const float* pdown_w = (const float*)d_in[8];
    const float* pdown_b = (const float*)d_in[9];
    const float* pup_w   = (const float*)d_in[10];
    const float* pup_b   = (const float*)d_in[11];
    const int*   task    = (const int*)d_in[12];

    float* qkv = (float*)d_ws;                       // [8192][3456]
    float* h1  = qkv + (size_t)kM * 3 * kDim;        // [8192][256]
    float* h2  = h1  + (size_t)kM * kMid;            // [8192][256]
    float* ao  = h2  + (size_t)kM * kMid;            // [8192][1152]
    float* out = (float*)d_out;

    // h1 = tanh(x @ down_w^T + down_b)     [runs iff task >= 4]
    gemm_xwt<true, false, true><<<dim3(kM / 128, kMid / 128), 256, 0, stream>>>(
        x, down_w, down_b, h1, kDim, kMid, task, 4);
    // h2 = tanh(x @ pdown_w^T + pdown_b)   [runs iff task >= 5]
    gemm_xwt<true, false, true><<<dim3(kM / 128, kMid / 128), 256, 0, stream>>>(
        x, pdown_w, pdown_b, h2, kDim, kMid, task, 5);
    // qkv = x @ Wqkv^T
    gemm_xwt<false, false, false><<<dim3(kM / 128, (3 * kDim) / 128), 256, 0, stream>>>(
        x, Wqkv, nullptr, qkv, kDim, 3 * kDim, nullptr, 0);
    // qkv[:,1152:] += h1 @ up_w^T + up_b   [task >= 4]
    gemm_xwt<false, true, true><<<dim3(kM / 128, (2 * kDim) / 128), 256, 0, stream>>>(
        h1, up_w, up_b, qkv + kDim, kMid, 3 * kDim, task, 4);
    // qkv[:,1152:] += h2 @ pup_w^T + pup_b [task >= 5]
    gemm_xwt<false, true, true><<<dim3(kM / 128, (2 * kDim) / 128), 256, 0, stream>>>(
        h2, pup_w, pup_b, qkv + kDim, kMid, 3 * kDim, task, 5);

    // attention: 112KB dynamic LDS
    hipFuncSetAttribute(reinterpret_cast<const void*>(attn_fwd),
                        hipFuncAttributeMaxDynamicSharedMemorySize, 114688);
    attn_fwd<<<dim3(kN / 64, kB * kHeads), 256, 114688, stream>>>(qkv, ao);

    // out = ao @ Wproj^T + bproj
    gemm_xwt<false, false, true><<<dim3(kM / 128, kDim / 128), 256, 0, stream>>>(
        ao, Wproj, bproj, out, kDim, kDim, nullptr, 0);

    // second output: down_w passthrough
    hipMemcpyAsync(out + (size_t)kM * kDim, down_w,
                   (size_t)kMid * kDim * sizeof(float),
                   hipMemcpyDeviceToDevice, stream);
}

// Round 2
// 605.819 us; speedup vs baseline: 4.2829x; 4.2829x over previous
//
#include <hip/hip_runtime.h>
#include <math.h>

namespace {

typedef unsigned short u16;
typedef __attribute__((ext_vector_type(8))) short short8;   // 8 bf16 = 4 VGPRs
typedef __attribute__((ext_vector_type(4))) float f32x4;

constexpr int kDim   = 1152;
constexpr int kHeads = 9;
constexpr int kMid   = 256;
constexpr int kB     = 8;
constexpr int kN     = 1024;
constexpr int kM     = kB * kN;                 // 8192 tokens
constexpr float kScale = 0.08838834764831845f;  // 128^-0.5

__device__ __forceinline__ u16 f2bf(float f) {
    unsigned u = __builtin_bit_cast(unsigned, f);
    return (u16)((u + 0x7FFFu + ((u >> 16) & 1u)) >> 16);
}
__device__ __forceinline__ float bf2f(u16 h) {
    unsigned u = ((unsigned)h) << 16;
    return __builtin_bit_cast(float, u);
}

// async global->LDS, 16B per lane. dst must be wave-uniform; lane i lands at dst + i*16.
__device__ __forceinline__ void gload_lds16(const void* g, void* l) {
    __builtin_amdgcn_global_load_lds(
        (const __attribute__((address_space(1))) unsigned int*)g,
        (__attribute__((address_space(3))) unsigned int*)l,
        16, 0, 0);
}

__global__ void cvt_bf16(const float* __restrict__ in, u16* __restrict__ out, int n4) {
    int i = blockIdx.x * blockDim.x + threadIdx.x;
    if (i < n4) {
        float4 v = reinterpret_cast<const float4*>(in)[i];
        ushort4 o;
        o.x = f2bf(v.x); o.y = f2bf(v.y); o.z = f2bf(v.z); o.w = f2bf(v.w);
        reinterpret_cast<ushort4*>(out)[i] = o;
    }
}

// ---------------------------------------------------------------------------
// bf16 MFMA GEMM, m97 structure: 128x128 tile, BK=64, 4 waves, 2-phase dbuf.
// C[m,n] = act(sum_k A[m,k]*Bw[n,k] + bias[n]) (+ C_old if ACCUM)
// A: [M,K] bf16 row-major. Bw: [N,K] bf16 row-major. K % 64 == 0.
// ---------------------------------------------------------------------------
template<bool TANH, bool ACCUM, bool BIAS, bool OUT_BF16>
__global__ __launch_bounds__(256)
void gemm_mfma(const u16* __restrict__ A, const u16* __restrict__ Bw,
               const float* __restrict__ bias, void* __restrict__ Cv,
               int K, int ldc, const int* __restrict__ taskp, int mintask)
{
    if (taskp != nullptr && *taskp < mintask) return;

    __shared__ u16 As[2][128 * 64];   // [row][k] row-major, 16KB each
    __shared__ u16 Bs[2][128 * 64];

    const int tid  = threadIdx.x;
    const int lane = tid & 63;
    const int wv   = tid >> 6;
    const int wr   = (wv >> 1) * 64;      // wave's C row offset within tile
    const int wc   = (wv & 1) * 64;       // wave's C col offset
    const int bm   = blockIdx.x * 128;
    const int bn   = blockIdx.y * 128;

    f32x4 acc[4][4] = {};

    const int srow = tid >> 3;   // staging row within 32-row slice
    const int sslt = tid & 7;    // staging 8-elem slot within row

    auto stage = [&](int buf, int k0) {
        const u16* ab = A  + (size_t)bm * K + k0;
        const u16* bb = Bw + (size_t)bn * K + k0;
#pragma unroll
        for (int i = 0; i < 4; ++i) {
            const int row = i * 32 + srow;
            gload_lds16(ab + (size_t)row * K + sslt * 8,
                        (char*)&As[buf][0] + (i * 256 + (tid & 192)) * 16);
        }
#pragma unroll
        for (int i = 0; i < 4; ++i) {
            const int row = i * 32 + srow;
            gload_lds16(bb + (size_t)row * K + sslt * 8,
                        (char*)&Bs[buf][0] + (i * 256 + (tid & 192)) * 16);
        }
    };

    stage(0, 0);
    const int nk = K >> 6;
    for (int kt = 0; kt < nk; ++kt) {
        __syncthreads();   // compiler drains vmcnt(0): buf[kt&1] ready for all waves
        if (kt + 1 < nk) stage((kt + 1) & 1, (kt + 1) * 64);
        const u16* as = &As[kt & 1][0];
        const u16* bs = &Bs[kt & 1][0];
#pragma unroll
        for (int ks = 0; ks < 2; ++ks) {
            short8 af[4], bf[4];
#pragma unroll
            for (int mi = 0; mi < 4; ++mi) {
                const int row = wr + mi * 16 + (lane & 15);
                af[mi] = *reinterpret_cast<const short8*>(as + row * 64 + ks * 32 + (lane >> 4) * 8);
            }
#pragma unroll
            for (int ni = 0; ni < 4; ++ni) {
                const int row = wc + ni * 16 + (lane & 15);
                bf[ni] = *reinterpret_cast<const short8*>(bs + row * 64 + ks * 32 + (lane >> 4) * 8);
            }
#pragma unroll
            for (int mi = 0; mi < 4; ++mi)
#pragma unroll
                for (int ni = 0; ni < 4; ++ni)
                    acc[mi][ni] = __builtin_amdgcn_mfma_f32_16x16x32_bf16(
                        af[mi], bf[ni], acc[mi][ni], 0, 0, 0);
        }
    }

    // epilogue: D frag -> C. col = lane&15, row = (lane>>4)*4 + r  [m89 verified]
#pragma unroll
    for (int mi = 0; mi < 4; ++mi) {
#pragma unroll
        for (int ni = 0; ni < 4; ++ni) {
            const int col = bn + wc + ni * 16 + (lane & 15);
            const float bv = BIAS ? bias[col] : 0.f;
#pragma unroll
            for (int r = 0; r < 4; ++r) {
                const int row = bm + wr + mi * 16 + (lane >> 4) * 4 + r;
                float v = acc[mi][ni][r] + bv;
                if (TANH) v = tanhf(v);
                if (OUT_BF16) {
                    u16* cp = (u16*)Cv + (size_t)row * ldc + col;
                    if (ACCUM) v += bf2f(*cp);
                    *cp = f2bf(v);
                } else {
                    float* cp = (float*)Cv + (size_t)row * ldc + col;
                    if (ACCUM) v += *cp;
                    *cp = v;
                }
            }
        }
    }
}

// ---------------------------------------------------------------------------
// MFMA flash attention, bf16. Block = 256 thr (4 waves) = one (b,h), 64 queries.
// Wave w owns q rows [w*16, w*16+16). KBLK=64. Q in regs; K, V^T, P in LDS
// with XOR swizzle byte ^= (row&7)<<4 (16-way conflict fix, G4).
// qkv: [8192][3456] bf16.  out: [8192][1152] bf16.
// ---------------------------------------------------------------------------
__global__ __launch_bounds__(256)
void attn_mfma(const u16* __restrict__ qkv, u16* __restrict__ out)
{
    __shared__ u16 Ks[64 * 128];      // [token][d], swizzled, 16KB
    __shared__ u16 Vt[128 * 64];      // [d][token], swizzled, 16KB
    __shared__ u16 Ps[4][16 * 64];    // per-wave [q][k], swizzled, 8KB

    const int bh  = blockIdx.x;              // 0..71 (same-bh blocks land on one XCD)
    const int b   = bh / kHeads;
    const int h   = bh - b * kHeads;
    const int q0  = blockIdx.y * 64;
    const int tid = threadIdx.x;
    const int lane = tid & 63;
    const int wv   = tid >> 6;
    const size_t rs = 3 * kDim;               // 3456
    const u16* base = qkv + (size_t)b * kN * rs;

    // Q fragments in registers (A-operand: row = lane&15, k = (lane>>4)*8+e)
    short8 qf[4];
    {
        const u16* qp = base + (size_t)(q0 + wv * 16 + (lane & 15)) * rs + h * 128;
#pragma unroll
        for (int ks = 0; ks < 4; ++ks)
            qf[ks] = *reinterpret_cast<const short8*>(qp + ks * 32 + (lane >> 4) * 8);
    }

    f32x4 O[8] = {};
    float m_i[4], l_i[4];
#pragma unroll
    for (int r = 0; r < 4; ++r) { m_i[r] = -INFINITY; l_i[r] = 0.f; }

    for (int kt = 0; kt < kN; kt += 64) {
        __syncthreads();   // prev tile's K/Vt readers done before overwrite

        // stage K via global_load_lds, source pre-swizzled (m173 pattern)
        {
            const u16* kb = base + (size_t)kt * rs + kDim + h * 128;
#pragma unroll
            for (int i = 0; i < 4; ++i) {
                const int e   = i * 256 + tid;     // 16B slot id 0..1023
                const int row = e >> 4;            // token
                const int s   = (e & 15) ^ (row & 7);
                gload_lds16(kb + (size_t)row * rs + s * 8,
                            (char*)Ks + (i * 256 + (tid & 192)) * 16);
            }
        }
        // stage V transposed via registers -> swizzled ds_write_b32 (token pairs)
        {
            const u16* vb = base + (size_t)kt * rs + 2 * kDim + h * 128;
#pragma unroll
            for (int i = 0; i < 2; ++i) {
                const int id = i * 256 + tid;      // 0..511
                const int tp = id >> 4;            // token pair 0..31
                const int c  = id & 15;            // d chunk (8 d's)
                const short8 v0 = *reinterpret_cast<const short8*>(vb + (size_t)(2 * tp) * rs + c * 8);
                const short8 v1 = *reinterpret_cast<const short8*>(vb + (size_t)(2 * tp + 1) * rs + c * 8);
#pragma unroll
                for (int j = 0; j < 8; ++j) {
                    const int d = c * 8 + j;
                    const unsigned val = (unsigned)(u16)v0[j] | ((unsigned)(u16)v1[j] << 16);
                    *(unsigned*)((char*)Vt + d * 128 + ((4 * tp) ^ ((d & 7) << 4))) = val;
                }
            }
        }
        __syncthreads();

        // S = Q K^T : A=Q(regs), B=K. D: q=(lane>>4)*4+r, k_tok=f*16+(lane&15)
        f32x4 sc[4] = {};
#pragma unroll
        for (int f = 0; f < 4; ++f) {
            const int tk = f * 16 + (lane & 15);
#pragma unroll
            for (int ks = 0; ks < 4; ++ks) {
                const short8 kf = *reinterpret_cast<const short8*>(
                    (const char*)Ks + tk * 256 + ((ks * 64 + (lane >> 4) * 16) ^ ((tk & 7) << 4)));
                sc[f] = __builtin_amdgcn_mfma_f32_16x16x32_bf16(qf[ks], kf, sc[f], 0, 0, 0);
            }
        }

        // online softmax (row q lives in one 16-lane group; reduce via shfl_xor)
        float mnew[4] = {-INFINITY, -INFINITY, -INFINITY, -INFINITY};
#pragma unroll
        for (int f = 0; f < 4; ++f)
#pragma unroll
            for (int r = 0; r < 4; ++r) {
                sc[f][r] *= kScale;
                mnew[r] = fmaxf(mnew[r], sc[f][r]);
            }
#pragma unroll
        for (int off = 1; off < 16; off <<= 1)
#pragma unroll
            for (int r = 0; r < 4; ++r)
                mnew[r] = fmaxf(mnew[r], __shfl_xor(mnew[r], off));

        float sf[4], rsum[4];
#pragma unroll
        for (int r = 0; r < 4; ++r) {
            const float mi = fmaxf(m_i[r], mnew[r]);
            sf[r] = __expf(m_i[r] - mi);   // first tile: exp(-inf)=0
            m_i[r] = mi;
            rsum[r] = 0.f;
        }
#pragma unroll
        for (int f = 0; f < 4; ++f)
#pragma unroll
            for (int r = 0; r < 4; ++r) {
                const float p = __expf(sc[f][r] - m_i[r]);
                rsum[r] += p;
                const int q = (lane >> 4) * 4 + r;
                const int k = f * 16 + (lane & 15);
                *(u16*)((char*)&Ps[wv][0] + q * 128 + ((k * 2) ^ ((q & 7) << 4))) = f2bf(p);
            }
#pragma unroll
        for (int off = 1; off < 16; off <<= 1)
#pragma unroll
            for (int r = 0; r < 4; ++r)
                rsum[r] += __shfl_xor(rsum[r], off);
#pragma unroll
        for (int r = 0; r < 4; ++r)
            l_i[r] = l_i[r] * sf[r] + rsum[r];
#pragma unroll
        for (int df = 0; df < 8; ++df)
#pragma unroll
            for (int r = 0; r < 4; ++r)
                O[df][r] *= sf[r];

        // O += P V : A=P (per-wave LDS round-trip), B=V^T
        short8 pa[2];
#pragma unroll
        for (int ks2 = 0; ks2 < 2; ++ks2) {
            const int q = lane & 15;
            pa[ks2] = *reinterpret_cast<const short8*>(
                (const char*)&Ps[wv][0] + q * 128 + ((ks2 * 64 + (lane >> 4) * 16) ^ ((q & 7) << 4)));
        }
#pragma unroll
        for (int df = 0; df < 8; ++df) {
            const int d = df * 16 + (lane & 15);
#pragma unroll
            for (int ks2 = 0; ks2 < 2; ++ks2) {
                const short8 vf = *reinterpret_cast<const short8*>(
                    (const char*)Vt + d * 128 + ((ks2 * 64 + (lane >> 4) * 16) ^ ((d & 7) << 4)));
                O[df] = __builtin_amdgcn_mfma_f32_16x16x32_bf16(pa[ks2], vf, O[df], 0, 0, 0);
            }
        }
    }

    // epilogue
    float inv[4];
#pragma unroll
    for (int r = 0; r < 4; ++r) inv[r] = 1.f / l_i[r];
#pragma unroll
    for (int df = 0; df < 8; ++df) {
        const int col = h * 128 + df * 16 + (lane & 15);
#pragma unroll
        for (int r = 0; r < 4; ++r) {
            const int row = b * kN + q0 + wv * 16 + (lane >> 4) * 4 + r;
            out[(size_t)row * kDim + col] = f2bf(O[df][r] * inv[r]);
        }
    }
}

}  // namespace

extern "C" void kernel_launch(void* const* d_in, const int* in_sizes, int n_in,
                              void* d_out, int out_size, void* d_ws, size_t ws_size,
                              hipStream_t stream)
{
    const float* x       = (const float*)d_in[0];
    const float* Wqkv    = (const float*)d_in[1];
    const float* Wproj   = (const float*)d_in[2];
    const float* bproj   = (const float*)d_in[3];
    const float* down_w  = (const float*)d_in[4];
    const float* down_b  = (const float*)d_in[5];
    const float* up_w    = (const float*)d_in[6];
    const float* up_b    = (const float*)d_in[7];
    const float* pdown_w = (const float*)d_in[8];
    const float* pdown_b = (const float*)d_in[9];
    const float* pup_w   = (const float*)d_in[10];
    const float* pup_b   = (const float*)d_in[11];
    const int*   task    = (const int*)d_in[12];

    // bf16 workspace layout (element offsets)
    u16* xb    = (u16*)d_ws;
    u16* wqkvb = xb    + (size_t)kM * kDim;        // 9,437,184
    u16* wprjb = wqkvb + (size_t)3 * kDim * kDim;  // 3,981,312
    u16* dwb   = wprjb + (size_t)kDim * kDim;      // 1,327,104
    u16* uwb   = dwb   + (size_t)kMid * kDim;      //   294,912
    u16* pdwb  = uwb   + (size_t)2 * kDim * kMid;  //   589,824
    u16* puwb  = pdwb  + (size_t)kMid * kDim;
    u16* h1b   = puwb  + (size_t)2 * kDim * kMid;
    u16* h2b   = h1b   + (size_t)kM * kMid;
    u16* qkvb  = h2b   + (size_t)kM * kMid;        // [8192][3456]
    u16* aob   = qkvb  + (size_t)kM * 3 * kDim;    // [8192][1152]
    float* out = (float*)d_out;

    auto cvt = [&](const float* s, u16* d, size_t n) {
        const int n4 = (int)(n / 4);
        cvt_bf16<<<(n4 + 255) / 256, 256, 0, stream>>>(s, d, n4);
    };
    cvt(x,       xb,    (size_t)kM * kDim);
    cvt(Wqkv,    wqkvb, (size_t)3 * kDim * kDim);
    cvt(Wproj,   wprjb, (size_t)kDim * kDim);
    cvt(down_w,  dwb,   (size_t)kMid * kDim);
    cvt(up_w,    uwb,   (size_t)2 * kDim * kMid);
    cvt(pdown_w, pdwb,  (size_t)kMid * kDim);
    cvt(pup_w,   puwb,  (size_t)2 * kDim * kMid);

    // h1 = tanh(x @ down_w^T + down_b)        [task >= 4]
    gemm_mfma<true, false, true, true><<<dim3(kM / 128, kMid / 128), 256, 0, stream>>>(
        xb, dwb, down_b, h1b, kDim, kMid, task, 4);
    // h2 = tanh(x @ pdown_w^T + pdown_b)      [task >= 5]
    gemm_mfma<true, false, true, true><<<dim3(kM / 128, kMid / 128), 256, 0, stream>>>(
        xb, pdwb, pdown_b, h2b, kDim, kMid, task, 5);
    // qkv = x @ Wqkv^T
    gemm_mfma<false, false, false, true><<<dim3(kM / 128, (3 * kDim) / 128), 256, 0, stream>>>(
        xb, wqkvb, nullptr, qkvb, kDim, 3 * kDim, nullptr, 0);
    // qkv[:,1152:] += h1 @ up_w^T + up_b      [task >= 4]
    gemm_mfma<false, true, true, true><<<dim3(kM / 128, (2 * kDim) / 128), 256, 0, stream>>>(
        h1b, uwb, up_b, qkvb + kDim, kMid, 3 * kDim, task, 4);
    // qkv[:,1152:] += h2 @ pup_w^T + pup_b    [task >= 5]
    gemm_mfma<false, true, true, true><<<dim3(kM / 128, (2 * kDim) / 128), 256, 0, stream>>>(
        h2b, puwb, pup_b, qkvb + kDim, kMid, 3 * kDim, task, 5);

    // attention (grid x=bh so same-bh q-blocks share an XCD: stride 72 % 8 == 0)
    attn_mfma<<<dim3(kB * kHeads, kN / 64), 256, 0, stream>>>(qkvb, aob);

    // out = attn_out @ Wproj^T + bproj  (fp32 output)
    gemm_mfma<false, false, true, false><<<dim3(kM / 128, kDim / 128), 256, 0, stream>>>(
        aob, wprjb, bproj, out, kDim, kDim, nullptr, 0);

    // second output: down_w passthrough
    hipMemcpyAsync(out + (size_t)kM * kDim, down_w,
                   (size_t)kMid * kDim * sizeof(float),
                   hipMemcpyDeviceToDevice, stream);
}

// Round 3
// 398.187 us; speedup vs baseline: 6.5161x; 1.5214x over previous
//
#include <hip/hip_runtime.h>
#include <math.h>

namespace {

typedef unsigned short u16;
typedef __attribute__((ext_vector_type(8))) short short8;   // 8 bf16 = 4 VGPRs
typedef __attribute__((ext_vector_type(4))) float f32x4;
typedef __attribute__((ext_vector_type(16))) float f32x16;

constexpr int kDim   = 1152;
constexpr int kHeads = 9;
constexpr int kMid   = 256;
constexpr int kB     = 8;
constexpr int kN     = 1024;
constexpr int kM     = kB * kN;                 // 8192 tokens
constexpr float kScale = 0.08838834764831845f;  // 128^-0.5

__device__ __forceinline__ u16 f2bf(float f) {
    unsigned u = __builtin_bit_cast(unsigned, f);
    return (u16)((u + 0x7FFFu + ((u >> 16) & 1u)) >> 16);
}
__device__ __forceinline__ float bf2f(u16 h) {
    unsigned u = ((unsigned)h) << 16;
    return __builtin_bit_cast(float, u);
}

// async global->LDS, 16B/lane. dst wave-uniform; lane i lands at dst + i*16.
__device__ __forceinline__ void gload_lds16(const void* g, void* l) {
    __builtin_amdgcn_global_load_lds(
        (const __attribute__((address_space(1))) unsigned int*)g,
        (__attribute__((address_space(3))) unsigned int*)l,
        16, 0, 0);
}

__device__ __forceinline__ unsigned cvtpk(float a, float b) {
    unsigned r;
    asm volatile("v_cvt_pk_bf16_f32 %0, %1, %2" : "=v"(r) : "v"(a), "v"(b));
    return r;  // lo16 = bf16(a), hi16 = bf16(b)
}

// exchange: x' = [x_lo, y_lo(partner)], y' = [x_hi(partner), y_hi]
__device__ __forceinline__ void halfswap(unsigned& x, unsigned& y, bool hihalf) {
    const unsigned xs = (unsigned)__shfl_xor((int)x, 32);
    const unsigned ys = (unsigned)__shfl_xor((int)y, 32);
    const unsigned nx = hihalf ? ys : x;
    const unsigned ny = hihalf ? y : xs;
    x = nx; y = ny;
}

// build PV B-operand frag (k = hi*8+e) from 8 same-q P values (ktok f(r,hi))
__device__ __forceinline__ short8 build_pfrag(float p0, float p1, float p2, float p3,
                                              float p4, float p5, float p6, float p7,
                                              bool hihalf) {
    unsigned x1 = cvtpk(p0, p1), y1 = cvtpk(p4, p5);
    unsigned x2 = cvtpk(p2, p3), y2 = cvtpk(p6, p7);
    halfswap(x1, y1, hihalf);
    halfswap(x2, y2, hihalf);
    union { unsigned u[4]; short8 s; } pk;
    pk.u[0] = x1; pk.u[1] = x2; pk.u[2] = y1; pk.u[3] = y2;
    return pk.s;
}

__global__ void cvt_bf16(const float* __restrict__ in, u16* __restrict__ out, int n4) {
    int i = blockIdx.x * blockDim.x + threadIdx.x;
    if (i < n4) {
        float4 v = reinterpret_cast<const float4*>(in)[i];
        ushort4 o;
        o.x = f2bf(v.x); o.y = f2bf(v.y); o.z = f2bf(v.z); o.w = f2bf(v.w);
        reinterpret_cast<ushort4*>(out)[i] = o;
    }
}

// rows of rl4 float4s from contiguous src into dst rows of stride dr4 (ushort4 units) at col off4
__global__ void cvt_bf16_strided(const float* __restrict__ in, u16* __restrict__ out,
                                 int n4, int rl4, int dr4, int off4) {
    int i = blockIdx.x * blockDim.x + threadIdx.x;
    if (i < n4) {
        float4 v = reinterpret_cast<const float4*>(in)[i];
        ushort4 o;
        o.x = f2bf(v.x); o.y = f2bf(v.y); o.z = f2bf(v.z); o.w = f2bf(v.w);
        const int r = i / rl4, c = i - r * rl4;
        reinterpret_cast<ushort4*>(out)[(size_t)r * dr4 + off4 + c] = o;
    }
}

// concatenated biases: bd[0:256]=down_b, bd[256:512]=pdown_b; bu = up_b (+ pup_b if task>=5)
__global__ void prep_bias(const float* __restrict__ down_b, const float* __restrict__ pdown_b,
                          const float* __restrict__ up_b, const float* __restrict__ pup_b,
                          const int* __restrict__ task,
                          float* __restrict__ bd, float* __restrict__ bu) {
    const bool t5 = (*task >= 5);
    for (int i = threadIdx.x; i < 512; i += blockDim.x)
        bd[i] = (i < 256) ? down_b[i] : pdown_b[i - 256];
    for (int i = threadIdx.x; i < 2304; i += blockDim.x)
        bu[i] = up_b[i] + (t5 ? pup_b[i] : 0.f);
}

// ---------------------------------------------------------------------------
// bf16 MFMA GEMM, m97 structure: 128x128 tile, BK=64, 4 waves, 2-phase dbuf.
// C[m,n] = act(sum_k A[m,k]*Bw[n,k] + bias[n]) (+ C_old if ACCUM)
// ---------------------------------------------------------------------------
template<bool TANH, bool ACCUM, bool BIAS, bool OUT_BF16, bool KSEL>
__global__ __launch_bounds__(256)
void gemm_mfma(const u16* __restrict__ A, const u16* __restrict__ Bw,
               const float* __restrict__ bias, void* __restrict__ Cv,
               int K, int lda, int ldb, int ldc,
               const int* __restrict__ taskp, int mintask)
{
    if (taskp != nullptr && *taskp < mintask) return;
    if (KSEL && *taskp < 5) K = 256;

    __shared__ u16 As[2][128 * 64];
    __shared__ u16 Bs[2][128 * 64];

    const int tid  = threadIdx.x;
    const int lane = tid & 63;
    const int wv   = tid >> 6;
    const int wr   = (wv >> 1) * 64;
    const int wc   = (wv & 1) * 64;
    const int bm   = blockIdx.x * 128;
    const int bn   = blockIdx.y * 128;

    f32x4 acc[4][4] = {};

    const int srow = tid >> 3;
    const int sslt = tid & 7;

    auto stage = [&](int buf, int k0) {
        const u16* ab = A  + (size_t)bm * lda + k0;
        const u16* bb = Bw + (size_t)bn * ldb + k0;
#pragma unroll
        for (int i = 0; i < 4; ++i) {
            const int row = i * 32 + srow;
            gload_lds16(ab + (size_t)row * lda + sslt * 8,
                        (char*)&As[buf][0] + (i * 256 + (tid & 192)) * 16);
        }
#pragma unroll
        for (int i = 0; i < 4; ++i) {
            const int row = i * 32 + srow;
            gload_lds16(bb + (size_t)row * ldb + sslt * 8,
                        (char*)&Bs[buf][0] + (i * 256 + (tid & 192)) * 16);
        }
    };

    stage(0, 0);
    const int nk = K >> 6;
    for (int kt = 0; kt < nk; ++kt) {
        __syncthreads();
        if (kt + 1 < nk) stage((kt + 1) & 1, (kt + 1) * 64);
        const u16* as = &As[kt & 1][0];
        const u16* bs = &Bs[kt & 1][0];
#pragma unroll
        for (int ks = 0; ks < 2; ++ks) {
            short8 af[4], bf[4];
#pragma unroll
            for (int mi = 0; mi < 4; ++mi) {
                const int row = wr + mi * 16 + (lane & 15);
                af[mi] = *reinterpret_cast<const short8*>(as + row * 64 + ks * 32 + (lane >> 4) * 8);
            }
#pragma unroll
            for (int ni = 0; ni < 4; ++ni) {
                const int row = wc + ni * 16 + (lane & 15);
                bf[ni] = *reinterpret_cast<const short8*>(bs + row * 64 + ks * 32 + (lane >> 4) * 8);
            }
#pragma unroll
            for (int mi = 0; mi < 4; ++mi)
#pragma unroll
                for (int ni = 0; ni < 4; ++ni)
                    acc[mi][ni] = __builtin_amdgcn_mfma_f32_16x16x32_bf16(
                        af[mi], bf[ni], acc[mi][ni], 0, 0, 0);
        }
    }

#pragma unroll
    for (int mi = 0; mi < 4; ++mi) {
#pragma unroll
        for (int ni = 0; ni < 4; ++ni) {
            const int col = bn + wc + ni * 16 + (lane & 15);
            const float bv = BIAS ? bias[col] : 0.f;
#pragma unroll
            for (int r = 0; r < 4; ++r) {
                const int row = bm + wr + mi * 16 + (lane >> 4) * 4 + r;
                float v = acc[mi][ni][r] + bv;
                if (TANH) v = tanhf(v);
                if (OUT_BF16) {
                    u16* cp = (u16*)Cv + (size_t)row * ldc + col;
                    if (ACCUM) v += bf2f(*cp);
                    *cp = f2bf(v);
                } else {
                    float* cp = (float*)Cv + (size_t)row * ldc + col;
                    if (ACCUM) v += *cp;
                    *cp = v;
                }
            }
        }
    }
}

// ---------------------------------------------------------------------------
// V transpose: qkv v-part [tok][d] -> vt[(b*9+h)*128 + d][tok]
// ---------------------------------------------------------------------------
__global__ __launch_bounds__(256)
void transpose_v(const u16* __restrict__ qkv, u16* __restrict__ vt)
{
    __shared__ u16 t[64][136];   // [tok][d], +8 pad
    const int bh = blockIdx.x, b = bh / kHeads, h = bh - b * kHeads;
    const int n0 = blockIdx.y * 64;
    const int tid = threadIdx.x;
#pragma unroll
    for (int it = 0; it < 4; ++it) {
        const int I = it * 256 + tid, tok = I >> 4, s = I & 15;
        *reinterpret_cast<short8*>(&t[tok][s * 8]) =
            *reinterpret_cast<const short8*>(
                qkv + (size_t)(b * kN + n0 + tok) * 3456 + 2304 + h * 128 + s * 8);
    }
    __syncthreads();
#pragma unroll
    for (int it = 0; it < 8; ++it) {
        const int I = it * 256 + tid;         // 0..2047 (8B units)
        const int d = I >> 4, tk = (I & 15) * 4;
        ushort4 v;
        v.x = t[tk + 0][d]; v.y = t[tk + 1][d];
        v.z = t[tk + 2][d]; v.w = t[tk + 3][d];
        *reinterpret_cast<ushort4*>(vt + (size_t)(bh * 128 + d) * kN + n0 + tk) = v;
    }
}

// ---------------------------------------------------------------------------
// MFMA flash attention, swapped-operand / in-register softmax (T12 structure).
// Block = 4 waves; wave w owns 32 q-rows. KVBLK = 64. 32x32x16 MFMA.
// S^T = mfma(K, Q): lane holds P[q=lane&31][32 ktok]. O^T = mfma(V^T, P^T):
// col = q stays lane-local, so softmax state (m, l, sf) is a lane scalar.
// K tile [64 tok][128 d] and V^T tile [128 d][64 tok] in LDS, XOR-swizzled
// byte ^= (row&7)<<4, staged via global_load_lds with pre-swizzled source.
// ---------------------------------------------------------------------------
__global__ __launch_bounds__(256)
void attn_mfma(const u16* __restrict__ qkv, const u16* __restrict__ vt,
               u16* __restrict__ out)
{
    __shared__ u16 Ks[64 * 128];   // 16 KB
    __shared__ u16 Vs[128 * 64];   // 16 KB

    const int bh = blockIdx.x, b = bh / kHeads, h = bh - b * kHeads;
    const int tid = threadIdx.x, lane = tid & 63, wv = tid >> 6;
    const int lo5 = lane & 31;
    const bool hihalf = (lane >= 32);
    const int hi = hihalf ? 1 : 0;
    const int q0 = blockIdx.y * 128 + wv * 32;

    // Q frags (B-operand): q = lo5, d = f*16 + hi*8 + e
    const u16* qp = qkv + (size_t)(b * kN + q0 + lo5) * 3456 + h * 128;
    short8 qf[8];
#pragma unroll
    for (int f = 0; f < 8; ++f)
        qf[f] = *reinterpret_cast<const short8*>(qp + f * 16 + hi * 8);

    // staging per-lane constant offsets (16B-unit index I per issue j)
    int koff[4], voff[4];
#pragma unroll
    for (int j = 0; j < 4; ++j) {
        const int I = (wv * 4 + j) * 64 + lane;
        const int tok = I >> 4, s = I & 15;
        koff[j] = tok * 3456 + ((s ^ (tok & 7)) * 8);
        const int d = I >> 3, sv = I & 7;
        voff[j] = d * kN + ((sv ^ (d & 7)) * 8);
    }
    const u16* kbase = qkv + (size_t)b * kN * 3456 + kDim + h * 128;
    const u16* vbase = vt + (size_t)bh * 128 * kN;

    f32x16 o[4] = {};
    float m = -INFINITY, l = 0.f;

    for (int kt = 0; kt < kN; kt += 64) {
        __syncthreads();   // prev tile's readers done
#pragma unroll
        for (int j = 0; j < 4; ++j)
            gload_lds16(kbase + (size_t)kt * 3456 + koff[j], (char*)Ks + (wv * 4 + j) * 1024);
#pragma unroll
        for (int j = 0; j < 4; ++j)
            gload_lds16(vbase + kt + voff[j], (char*)Vs + (wv * 4 + j) * 1024);
        __syncthreads();   // vmcnt(0) drained by compiler before barrier

        // S^T = K Q^T : A = K rows (ktok), B = Q. col(q)=lo5
        f32x16 s0 = {}, s1 = {};
#pragma unroll
        for (int f = 0; f < 8; ++f) {
            const int c = (f * 2 + hi) * 16;
            const int swz = (lo5 & 7) << 4;
            const short8 ka = *reinterpret_cast<const short8*>(
                (const char*)Ks + lo5 * 256 + (c ^ swz));
            const short8 kb = *reinterpret_cast<const short8*>(
                (const char*)Ks + (lo5 + 32) * 256 + (c ^ swz));
            s0 = __builtin_amdgcn_mfma_f32_32x32x16_bf16(ka, qf[f], s0, 0, 0, 0);
            s1 = __builtin_amdgcn_mfma_f32_32x32x16_bf16(kb, qf[f], s1, 0, 0, 0);
        }

        // online softmax — fully lane-local except one shfl_xor(32) pair
        float mx = s0[0];
#pragma unroll
        for (int r = 1; r < 16; ++r) mx = fmaxf(mx, s0[r]);
#pragma unroll
        for (int r = 0; r < 16; ++r) mx = fmaxf(mx, s1[r]);
        mx = fmaxf(mx, __shfl_xor(mx, 32));
        const float mnew = fmaxf(m, mx);
        const float sf = __expf((m - mnew) * kScale);   // first tile: exp(-inf)=0
        m = mnew;

        float rsum = 0.f;
#pragma unroll
        for (int r = 0; r < 16; ++r) { s0[r] = __expf((s0[r] - m) * kScale); rsum += s0[r]; }
#pragma unroll
        for (int r = 0; r < 16; ++r) { s1[r] = __expf((s1[r] - m) * kScale); rsum += s1[r]; }
        rsum += __shfl_xor(rsum, 32);
        l = l * sf + rsum;
#pragma unroll
        for (int dt = 0; dt < 4; ++dt)
#pragma unroll
            for (int r = 0; r < 16; ++r) o[dt][r] *= sf;

        // P frags (B-operand, k = hi*8+e per 16-ktok chunk)
        short8 pf[4];
        pf[0] = build_pfrag(s0[0], s0[1], s0[2], s0[3], s0[4], s0[5], s0[6], s0[7], hihalf);
        pf[1] = build_pfrag(s0[8], s0[9], s0[10], s0[11], s0[12], s0[13], s0[14], s0[15], hihalf);
        pf[2] = build_pfrag(s1[0], s1[1], s1[2], s1[3], s1[4], s1[5], s1[6], s1[7], hihalf);
        pf[3] = build_pfrag(s1[8], s1[9], s1[10], s1[11], s1[12], s1[13], s1[14], s1[15], hihalf);

        // O^T += V^T P : A = V^T rows (d), B = P^T. col(q)=lo5
#pragma unroll
        for (int dt = 0; dt < 4; ++dt) {
            const int drow = dt * 32 + lo5;
            const int swz = (lo5 & 7) << 4;
#pragma unroll
            for (int c = 0; c < 4; ++c) {
                const int col = (c * 2 + hi) * 16;
                const short8 va = *reinterpret_cast<const short8*>(
                    (const char*)Vs + drow * 128 + (col ^ swz));
                o[dt] = __builtin_amdgcn_mfma_f32_32x32x16_bf16(va, pf[c], o[dt], 0, 0, 0);
            }
        }
    }

    // epilogue: lane holds O^T[d][q=lo5]; d = dt*32 + 8*rg + 4*hi + r
    const float inv = 1.f / l;
    u16* op = out + (size_t)(b * kN + q0 + lo5) * kDim + h * 128;
#pragma unroll
    for (int dt = 0; dt < 4; ++dt) {
#pragma unroll
        for (int rg = 0; rg < 4; ++rg) {
            const int d0 = dt * 32 + rg * 8 + hi * 4;
            ushort4 v;
            v.x = f2bf(o[dt][rg * 4 + 0] * inv);
            v.y = f2bf(o[dt][rg * 4 + 1] * inv);
            v.z = f2bf(o[dt][rg * 4 + 2] * inv);
            v.w = f2bf(o[dt][rg * 4 + 3] * inv);
            *reinterpret_cast<ushort4*>(op + d0) = v;
        }
    }
}

}  // namespace

extern "C" void kernel_launch(void* const* d_in, const int* in_sizes, int n_in,
                              void* d_out, int out_size, void* d_ws, size_t ws_size,
                              hipStream_t stream)
{
    const float* x       = (const float*)d_in[0];
    const float* Wqkv    = (const float*)d_in[1];
    const float* Wproj   = (const float*)d_in[2];
    const float* bproj   = (const float*)d_in[3];
    const float* down_w  = (const float*)d_in[4];
    const float* down_b  = (const float*)d_in[5];
    const float* up_w    = (const float*)d_in[6];
    const float* up_b    = (const float*)d_in[7];
    const float* pdown_w = (const float*)d_in[8];
    const float* pdown_b = (const float*)d_in[9];
    const float* pup_w   = (const float*)d_in[10];
    const float* pup_b   = (const float*)d_in[11];
    const int*   task    = (const int*)d_in[12];

    // ws layout (u16 elements). xb and vt share a region (x dead before vt written).
    u16* xb_vt  = (u16*)d_ws;                          //  9,437,184
    u16* wqkvb  = xb_vt  + (size_t)kM * kDim;          //  3,981,312
    u16* wprjb  = wqkvb  + (size_t)3 * kDim * kDim;    //  1,327,104
    u16* wdownb = wprjb  + (size_t)kDim * kDim;        //    589,824 [512][1152]
    u16* wupb   = wdownb + (size_t)512 * kDim;         //  1,179,648 [2304][512]
    u16* h12    = wupb   + (size_t)2304 * 512;         //  4,194,304 [8192][512]
    u16* qkvb   = h12    + (size_t)kM * 512;           // 28,311,552 [8192][3456]
    u16* aob    = qkvb   + (size_t)kM * 3 * kDim;      //  9,437,184 [8192][1152]
    float* bd   = (float*)(aob + (size_t)kM * kDim);   // 512 f32
    float* bu   = bd + 512;                            // 2304 f32
    float* out  = (float*)d_out;
    u16* xb = xb_vt;
    u16* vt = xb_vt;

    auto cvt = [&](const float* s, u16* d, size_t n) {
        const int n4 = (int)(n / 4);
        cvt_bf16<<<(n4 + 255) / 256, 256, 0, stream>>>(s, d, n4);
    };
    cvt(x,       xb,                  (size_t)kM * kDim);
    cvt(Wqkv,    wqkvb,               (size_t)3 * kDim * kDim);
    cvt(Wproj,   wprjb,               (size_t)kDim * kDim);
    cvt(down_w,  wdownb,              (size_t)kMid * kDim);
    cvt(pdown_w, wdownb + 256 * kDim, (size_t)kMid * kDim);
    {   // up/pup interleaved by K into [2304][512]
        const int n4 = 2304 * 64;
        cvt_bf16_strided<<<(n4 + 255) / 256, 256, 0, stream>>>(up_w,  wupb, n4, 64, 128, 0);
        cvt_bf16_strided<<<(n4 + 255) / 256, 256, 0, stream>>>(pup_w, wupb, n4, 64, 128, 64);
    }
    prep_bias<<<1, 256, 0, stream>>>(down_b, pdown_b, up_b, pup_b, task, bd, bu);

    // h12 = tanh(x @ [down_w;pdown_w]^T + bd)  (unconditional; unused cols harmless)
    gemm_mfma<true, false, true, true, false><<<dim3(kM / 128, 4), 256, 0, stream>>>(
        xb, wdownb, bd, h12, kDim, kDim, kDim, 512, nullptr, 0);
    // qkv = x @ Wqkv^T
    gemm_mfma<false, false, false, true, false><<<dim3(kM / 128, 27), 256, 0, stream>>>(
        xb, wqkvb, nullptr, qkvb, kDim, kDim, kDim, 3 * kDim, nullptr, 0);
    // qkv[:,1152:] += h12 @ wupb^T + bu   [task>=4; K = task>=5 ? 512 : 256]
    gemm_mfma<false, true, true, true, true><<<dim3(kM / 128, 18), 256, 0, stream>>>(
        h12, wupb, bu, qkvb + kDim, 512, 512, 512, 3 * kDim, task, 4);

    // vt[(b*9+h)*128+d][tok] = V  (overwrites xb region — x no longer needed)
    transpose_v<<<dim3(kB * kHeads, kN / 64), 256, 0, stream>>>(qkvb, vt);

    // attention
    attn_mfma<<<dim3(kB * kHeads, kN / 128), 256, 0, stream>>>(qkvb, vt, aob);

    // out = attn_out @ Wproj^T + bproj  (fp32)
    gemm_mfma<false, false, true, false, false><<<dim3(kM / 128, 9), 256, 0, stream>>>(
        aob, wprjb, bproj, out, kDim, kDim, kDim, kDim, nullptr, 0);

    // second output: down_w passthrough
    hipMemcpyAsync(out + (size_t)kM * kDim, down_w,
                   (size_t)kMid * kDim * sizeof(float),
                   hipMemcpyDeviceToDevice, stream);
}

// Round 4
// 376.491 us; speedup vs baseline: 6.8917x; 1.0576x over previous
//
#include <hip/hip_runtime.h>
#include <math.h>

namespace {

typedef unsigned short u16;
typedef __attribute__((ext_vector_type(8))) short short8;   // 8 bf16 = 4 VGPRs
typedef __attribute__((ext_vector_type(4))) float f32x4;
typedef __attribute__((ext_vector_type(16))) float f32x16;

constexpr int kDim   = 1152;
constexpr int kHeads = 9;
constexpr int kMid   = 256;
constexpr int kB     = 8;
constexpr int kN     = 1024;
constexpr int kM     = kB * kN;                 // 8192 tokens
constexpr int kQS    = 3584;                    // padded qkv row stride (14*256)
constexpr float kScale = 0.08838834764831845f;  // 128^-0.5

__device__ __forceinline__ u16 f2bf(float f) {
    unsigned u = __builtin_bit_cast(unsigned, f);
    return (u16)((u + 0x7FFFu + ((u >> 16) & 1u)) >> 16);
}
__device__ __forceinline__ float bf2f(u16 h) {
    unsigned u = ((unsigned)h) << 16;
    return __builtin_bit_cast(float, u);
}

// async global->LDS, 16B/lane. dst wave-uniform; lane i lands at dst + i*16.
__device__ __forceinline__ void gload_lds16(const void* g, void* l) {
    __builtin_amdgcn_global_load_lds(
        (const __attribute__((address_space(1))) unsigned int*)g,
        (__attribute__((address_space(3))) unsigned int*)l,
        16, 0, 0);
}

__device__ __forceinline__ unsigned cvtpk(float a, float b) {
    unsigned r;
    asm volatile("v_cvt_pk_bf16_f32 %0, %1, %2" : "=v"(r) : "v"(a), "v"(b));
    return r;  // lo16 = bf16(a), hi16 = bf16(b)
}

// exchange: x' = [x_lo, y_lo(partner)], y' = [x_hi(partner), y_hi]
__device__ __forceinline__ void halfswap(unsigned& x, unsigned& y, bool hihalf) {
    const unsigned xs = (unsigned)__shfl_xor((int)x, 32);
    const unsigned ys = (unsigned)__shfl_xor((int)y, 32);
    const unsigned nx = hihalf ? ys : x;
    const unsigned ny = hihalf ? y : xs;
    x = nx; y = ny;
}

__device__ __forceinline__ short8 build_pfrag(float p0, float p1, float p2, float p3,
                                              float p4, float p5, float p6, float p7,
                                              bool hihalf) {
    unsigned x1 = cvtpk(p0, p1), y1 = cvtpk(p4, p5);
    unsigned x2 = cvtpk(p2, p3), y2 = cvtpk(p6, p7);
    halfswap(x1, y1, hihalf);
    halfswap(x2, y2, hihalf);
    union { unsigned u[4]; short8 s; } pk;
    pk.u[0] = x1; pk.u[1] = x2; pk.u[2] = y1; pk.u[3] = y2;
    return pk.s;
}

__global__ void cvt_bf16(const float* __restrict__ in, u16* __restrict__ out, int n4) {
    int i = blockIdx.x * blockDim.x + threadIdx.x;
    if (i < n4) {
        float4 v = reinterpret_cast<const float4*>(in)[i];
        ushort4 o;
        o.x = f2bf(v.x); o.y = f2bf(v.y); o.z = f2bf(v.z); o.w = f2bf(v.w);
        reinterpret_cast<ushort4*>(out)[i] = o;
    }
}

__global__ void cvt_bf16_strided(const float* __restrict__ in, u16* __restrict__ out,
                                 int n4, int rl4, int dr4, int off4) {
    int i = blockIdx.x * blockDim.x + threadIdx.x;
    if (i < n4) {
        float4 v = reinterpret_cast<const float4*>(in)[i];
        ushort4 o;
        o.x = f2bf(v.x); o.y = f2bf(v.y); o.z = f2bf(v.z); o.w = f2bf(v.w);
        const int r = i / rl4, c = i - r * rl4;
        reinterpret_cast<ushort4*>(out)[(size_t)r * dr4 + off4 + c] = o;
    }
}

__global__ void prep_bias(const float* __restrict__ down_b, const float* __restrict__ pdown_b,
                          const float* __restrict__ up_b, const float* __restrict__ pup_b,
                          const int* __restrict__ task,
                          float* __restrict__ bd, float* __restrict__ bu) {
    const bool t5 = (*task >= 5);
    for (int i = threadIdx.x; i < 512; i += blockDim.x)
        bd[i] = (i < 256) ? down_b[i] : pdown_b[i - 256];
    for (int i = threadIdx.x; i < 2304; i += blockDim.x)
        bu[i] = up_b[i] + (t5 ? pup_b[i] : 0.f);
}

// ---------------------------------------------------------------------------
// 256x256 tile GEMM, BK=32, 8 waves, 4-deep LDS pipeline with counted vmcnt
// (T3/T4 mechanism: loads stay in flight across barriers, never drained to 0
// in steady state; one barrier per K-tile; 32 MFMA per barrier per wave).
// LDS frag reads bank-conflict-free via slot ^= (row>>1)&3 swizzle; staging
// keeps LDS linear and pre-swizzles the global source (m173 / rule #21).
// ---------------------------------------------------------------------------
template<bool ACCUM, bool BIAS, bool KSEL>
__global__ __launch_bounds__(512, 2)
void gemm256(const u16* __restrict__ A, const u16* __restrict__ Bw,
             const float* __restrict__ bias, u16* __restrict__ C,
             int K, int lda, int ldb, int ldc,
             const int* __restrict__ taskp, int mintask)
{
    if (taskp != nullptr && *taskp < mintask) return;
    if (KSEL && *taskp < 5) K = 256;

    extern __shared__ u16 lds[];           // 128 KiB: LA[4][8192], LB[4][8192]
    u16* LA = lds;
    u16* LB = lds + 4 * 8192;

    const int tid  = threadIdx.x;
    const int lane = tid & 63;
    const int wid  = tid >> 6;
    const int wm   = wid >> 2;             // 0..1 : wave row-half (128 rows)
    const int wn   = wid & 3;              // 0..3 : wave col-quarter (64 cols)
    const int bm   = blockIdx.x * 256;
    const int bn   = blockIdx.y * 256;

    // staging geometry: K-tile = [256 rows][32 k] per matrix; 2 issues each.
    int srow[2], scol[2];
#pragma unroll
    for (int i = 0; i < 2; ++i) {
        const int L = i * 512 + tid;       // 16B slot 0..1023
        srow[i] = L >> 2;
        const int slot = L & 3;
        scol[i] = (slot ^ ((srow[i] >> 1) & 3)) * 8;   // inverse-swizzled source
    }
    const int ldst0 = (0 * 512 + wid * 64) * 16;       // wave-uniform LDS byte bases
    const int ldst1 = (1 * 512 + wid * 64) * 16;

    auto stage = [&](int q, int kt) {
        const u16* ag = A  + (size_t)bm * lda + kt * 32;
        const u16* bg = Bw + (size_t)bn * ldb + kt * 32;
        gload_lds16(ag + (size_t)srow[0] * lda + scol[0], (char*)(LA + q * 8192) + ldst0);
        gload_lds16(ag + (size_t)srow[1] * lda + scol[1], (char*)(LA + q * 8192) + ldst1);
        gload_lds16(bg + (size_t)srow[0] * ldb + scol[0], (char*)(LB + q * 8192) + ldst0);
        gload_lds16(bg + (size_t)srow[1] * ldb + scol[1], (char*)(LB + q * 8192) + ldst1);
    };

    f32x4 acc[8][4] = {};
    const int nk = K >> 5;

    stage(0, 0); stage(1, 1); stage(2, 2);   // 12 loads in flight

    for (int kt = 0; kt < nk; ++kt) {
        const int ahead = nk - 1 - kt;       // K-tiles staged after kt
        if (ahead >= 2)      asm volatile("s_waitcnt vmcnt(8)" ::: "memory");
        else if (ahead == 1) asm volatile("s_waitcnt vmcnt(4)" ::: "memory");
        else                 asm volatile("s_waitcnt vmcnt(0)" ::: "memory");
        __builtin_amdgcn_sched_barrier(0);
        __builtin_amdgcn_s_barrier();        // all waves: tile kt in LDS; tile kt-1 readers done

        if (kt + 3 < nk) stage((kt + 3) & 3, kt + 3);   // overwrites slot (kt-1)&3: safe

        const u16* as = LA + (kt & 3) * 8192;
        const u16* bs = LB + (kt & 3) * 8192;
        short8 af[8], bf[4];
#pragma unroll
        for (int mi = 0; mi < 8; ++mi) {
            const int row = wm * 128 + mi * 16 + (lane & 15);
            af[mi] = *reinterpret_cast<const short8*>(
                (const char*)as + row * 64 + (((lane >> 4) ^ ((row >> 1) & 3)) * 16));
        }
#pragma unroll
        for (int ni = 0; ni < 4; ++ni) {
            const int row = wn * 64 + ni * 16 + (lane & 15);
            bf[ni] = *reinterpret_cast<const short8*>(
                (const char*)bs + row * 64 + (((lane >> 4) ^ ((row >> 1) & 3)) * 16));
        }
        __builtin_amdgcn_s_setprio(1);
#pragma unroll
        for (int mi = 0; mi < 8; ++mi)
#pragma unroll
            for (int ni = 0; ni < 4; ++ni)
                acc[mi][ni] = __builtin_amdgcn_mfma_f32_16x16x32_bf16(
                    af[mi], bf[ni], acc[mi][ni], 0, 0, 0);
        __builtin_amdgcn_s_setprio(0);
    }

    // epilogue: col = lane&15, row = (lane>>4)*4 + r within each 16x16 frag
#pragma unroll
    for (int mi = 0; mi < 8; ++mi) {
#pragma unroll
        for (int ni = 0; ni < 4; ++ni) {
            const int col = bn + wn * 64 + ni * 16 + (lane & 15);
            const float bv = BIAS ? bias[col] : 0.f;
#pragma unroll
            for (int r = 0; r < 4; ++r) {
                const int row = bm + wm * 128 + mi * 16 + (lane >> 4) * 4 + r;
                float v = acc[mi][ni][r] + bv;
                u16* cp = C + (size_t)row * ldc + col;
                if (ACCUM) v += bf2f(*cp);
                *cp = f2bf(v);
            }
        }
    }
}

// ---------------------------------------------------------------------------
// bf16 MFMA GEMM, m97 structure: 128x128 tile, BK=64, 4 waves, 2-phase dbuf.
// Used for the small-N GEMMs (h12: N=512, proj: N=1152) where 256^2 grids
// would under-fill the 256 CUs.
// ---------------------------------------------------------------------------
template<bool TANH, bool ACCUM, bool BIAS, bool OUT_BF16>
__global__ __launch_bounds__(256)
void gemm_mfma(const u16* __restrict__ A, const u16* __restrict__ Bw,
               const float* __restrict__ bias, void* __restrict__ Cv,
               int K, int lda, int ldb, int ldc,
               const int* __restrict__ taskp, int mintask)
{
    if (taskp != nullptr && *taskp < mintask) return;

    __shared__ u16 As[2][128 * 64];
    __shared__ u16 Bs[2][128 * 64];

    const int tid  = threadIdx.x;
    const int lane = tid & 63;
    const int wv   = tid >> 6;
    const int wr   = (wv >> 1) * 64;
    const int wc   = (wv & 1) * 64;
    const int bm   = blockIdx.x * 128;
    const int bn   = blockIdx.y * 128;

    f32x4 acc[4][4] = {};

    const int srow = tid >> 3;
    const int sslt = tid & 7;

    auto stage = [&](int buf, int k0) {
        const u16* ab = A  + (size_t)bm * lda + k0;
        const u16* bb = Bw + (size_t)bn * ldb + k0;
#pragma unroll
        for (int i = 0; i < 4; ++i) {
            const int row = i * 32 + srow;
            gload_lds16(ab + (size_t)row * lda + sslt * 8,
                        (char*)&As[buf][0] + (i * 256 + (tid & 192)) * 16);
        }
#pragma unroll
        for (int i = 0; i < 4; ++i) {
            const int row = i * 32 + srow;
            gload_lds16(bb + (size_t)row * ldb + sslt * 8,
                        (char*)&Bs[buf][0] + (i * 256 + (tid & 192)) * 16);
        }
    };

    stage(0, 0);
    const int nk = K >> 6;
    for (int kt = 0; kt < nk; ++kt) {
        __syncthreads();
        if (kt + 1 < nk) stage((kt + 1) & 1, (kt + 1) * 64);
        const u16* as = &As[kt & 1][0];
        const u16* bs = &Bs[kt & 1][0];
#pragma unroll
        for (int ks = 0; ks < 2; ++ks) {
            short8 af[4], bf[4];
#pragma unroll
            for (int mi = 0; mi < 4; ++mi) {
                const int row = wr + mi * 16 + (lane & 15);
                af[mi] = *reinterpret_cast<const short8*>(as + row * 64 + ks * 32 + (lane >> 4) * 8);
            }
#pragma unroll
            for (int ni = 0; ni < 4; ++ni) {
                const int row = wc + ni * 16 + (lane & 15);
                bf[ni] = *reinterpret_cast<const short8*>(bs + row * 64 + ks * 32 + (lane >> 4) * 8);
            }
#pragma unroll
            for (int mi = 0; mi < 4; ++mi)
#pragma unroll
                for (int ni = 0; ni < 4; ++ni)
                    acc[mi][ni] = __builtin_amdgcn_mfma_f32_16x16x32_bf16(
                        af[mi], bf[ni], acc[mi][ni], 0, 0, 0);
        }
    }

#pragma unroll
    for (int mi = 0; mi < 4; ++mi) {
#pragma unroll
        for (int ni = 0; ni < 4; ++ni) {
            const int col = bn + wc + ni * 16 + (lane & 15);
            const float bv = BIAS ? bias[col] : 0.f;
#pragma unroll
            for (int r = 0; r < 4; ++r) {
                const int row = bm + wr + mi * 16 + (lane >> 4) * 4 + r;
                float v = acc[mi][ni][r] + bv;
                if (TANH) v = tanhf(v);
                if (OUT_BF16) {
                    u16* cp = (u16*)Cv + (size_t)row * ldc + col;
                    if (ACCUM) v += bf2f(*cp);
                    *cp = f2bf(v);
                } else {
                    float* cp = (float*)Cv + (size_t)row * ldc + col;
                    if (ACCUM) v += *cp;
                    *cp = v;
                }
            }
        }
    }
}

// ---------------------------------------------------------------------------
// V transpose: qkv v-part [tok][d] -> vt[(b*9+h)*128 + d][tok]
// ---------------------------------------------------------------------------
__global__ __launch_bounds__(256)
void transpose_v(const u16* __restrict__ qkv, u16* __restrict__ vt)
{
    __shared__ u16 t[64][136];   // [tok][d], +8 pad
    const int bh = blockIdx.x, b = bh / kHeads, h = bh - b * kHeads;
    const int n0 = blockIdx.y * 64;
    const int tid = threadIdx.x;
#pragma unroll
    for (int it = 0; it < 4; ++it) {
        const int I = it * 256 + tid, tok = I >> 4, s = I & 15;
        *reinterpret_cast<short8*>(&t[tok][s * 8]) =
            *reinterpret_cast<const short8*>(
                qkv + (size_t)(b * kN + n0 + tok) * kQS + 2304 + h * 128 + s * 8);
    }
    __syncthreads();
#pragma unroll
    for (int it = 0; it < 8; ++it) {
        const int I = it * 256 + tid;
        const int d = I >> 4, tk = (I & 15) * 4;
        ushort4 v;
        v.x = t[tk + 0][d]; v.y = t[tk + 1][d];
        v.z = t[tk + 2][d]; v.w = t[tk + 3][d];
        *reinterpret_cast<ushort4*>(vt + (size_t)(bh * 128 + d) * kN + n0 + tk) = v;
    }
}

// ---------------------------------------------------------------------------
// MFMA flash attention, swapped-operand / in-register softmax (T12 structure).
// ---------------------------------------------------------------------------
__global__ __launch_bounds__(256)
void attn_mfma(const u16* __restrict__ qkv, const u16* __restrict__ vt,
               u16* __restrict__ out)
{
    __shared__ u16 Ks[64 * 128];   // 16 KB
    __shared__ u16 Vs[128 * 64];   // 16 KB

    const int bh = blockIdx.x, b = bh / kHeads, h = bh - b * kHeads;
    const int tid = threadIdx.x, lane = tid & 63, wv = tid >> 6;
    const int lo5 = lane & 31;
    const bool hihalf = (lane >= 32);
    const int hi = hihalf ? 1 : 0;
    const int q0 = blockIdx.y * 128 + wv * 32;

    const u16* qp = qkv + (size_t)(b * kN + q0 + lo5) * kQS + h * 128;
    short8 qf[8];
#pragma unroll
    for (int f = 0; f < 8; ++f)
        qf[f] = *reinterpret_cast<const short8*>(qp + f * 16 + hi * 8);

    int koff[4], voff[4];
#pragma unroll
    for (int j = 0; j < 4; ++j) {
        const int I = (wv * 4 + j) * 64 + lane;
        const int tok = I >> 4, s = I & 15;
        koff[j] = tok * kQS + ((s ^ (tok & 7)) * 8);
        const int d = I >> 3, sv = I & 7;
        voff[j] = d * kN + ((sv ^ (d & 7)) * 8);
    }
    const u16* kbase = qkv + (size_t)b * kN * kQS + kDim + h * 128;
    const u16* vbase = vt + (size_t)bh * 128 * kN;

    f32x16 o[4] = {};
    float m = -INFINITY, l = 0.f;

    for (int kt = 0; kt < kN; kt += 64) {
        __syncthreads();
#pragma unroll
        for (int j = 0; j < 4; ++j)
            gload_lds16(kbase + (size_t)kt * kQS + koff[j], (char*)Ks + (wv * 4 + j) * 1024);
#pragma unroll
        for (int j = 0; j < 4; ++j)
            gload_lds16(vbase + kt + voff[j], (char*)Vs + (wv * 4 + j) * 1024);
        __syncthreads();

        f32x16 s0 = {}, s1 = {};
#pragma unroll
        for (int f = 0; f < 8; ++f) {
            const int c = (f * 2 + hi) * 16;
            const int swz = (lo5 & 7) << 4;
            const short8 ka = *reinterpret_cast<const short8*>(
                (const char*)Ks + lo5 * 256 + (c ^ swz));
            const short8 kb = *reinterpret_cast<const short8*>(
                (const char*)Ks + (lo5 + 32) * 256 + (c ^ swz));
            s0 = __builtin_amdgcn_mfma_f32_32x32x16_bf16(ka, qf[f], s0, 0, 0, 0);
            s1 = __builtin_amdgcn_mfma_f32_32x32x16_bf16(kb, qf[f], s1, 0, 0, 0);
        }

        float mx = s0[0];
#pragma unroll
        for (int r = 1; r < 16; ++r) mx = fmaxf(mx, s0[r]);
#pragma unroll
        for (int r = 0; r < 16; ++r) mx = fmaxf(mx, s1[r]);
        mx = fmaxf(mx, __shfl_xor(mx, 32));
        const float mnew = fmaxf(m, mx);
        const float sf = __expf((m - mnew) * kScale);
        m = mnew;

        float rsum = 0.f;
#pragma unroll
        for (int r = 0; r < 16; ++r) { s0[r] = __expf((s0[r] - m) * kScale); rsum += s0[r]; }
#pragma unroll
        for (int r = 0; r < 16; ++r) { s1[r] = __expf((s1[r] - m) * kScale); rsum += s1[r]; }
        rsum += __shfl_xor(rsum, 32);
        l = l * sf + rsum;
#pragma unroll
        for (int dt = 0; dt < 4; ++dt)
#pragma unroll
            for (int r = 0; r < 16; ++r) o[dt][r] *= sf;

        short8 pf[4];
        pf[0] = build_pfrag(s0[0], s0[1], s0[2], s0[3], s0[4], s0[5], s0[6], s0[7], hihalf);
        pf[1] = build_pfrag(s0[8], s0[9], s0[10], s0[11], s0[12], s0[13], s0[14], s0[15], hihalf);
        pf[2] = build_pfrag(s1[0], s1[1], s1[2], s1[3], s1[4], s1[5], s1[6], s1[7], hihalf);
        pf[3] = build_pfrag(s1[8], s1[9], s1[10], s1[11], s1[12], s1[13], s1[14], s1[15], hihalf);

#pragma unroll
        for (int dt = 0; dt < 4; ++dt) {
            const int drow = dt * 32 + lo5;
            const int swz = (lo5 & 7) << 4;
#pragma unroll
            for (int c = 0; c < 4; ++c) {
                const int col = (c * 2 + hi) * 16;
                const short8 va = *reinterpret_cast<const short8*>(
                    (const char*)Vs + drow * 128 + (col ^ swz));
                o[dt] = __builtin_amdgcn_mfma_f32_32x32x16_bf16(va, pf[c], o[dt], 0, 0, 0);
            }
        }
    }

    const float inv = 1.f / l;
    u16* op = out + (size_t)(b * kN + q0 + lo5) * kDim + h * 128;
#pragma unroll
    for (int dt = 0; dt < 4; ++dt) {
#pragma unroll
        for (int rg = 0; rg < 4; ++rg) {
            const int d0 = dt * 32 + rg * 8 + hi * 4;
            ushort4 v;
            v.x = f2bf(o[dt][rg * 4 + 0] * inv);
            v.y = f2bf(o[dt][rg * 4 + 1] * inv);
            v.z = f2bf(o[dt][rg * 4 + 2] * inv);
            v.w = f2bf(o[dt][rg * 4 + 3] * inv);
            *reinterpret_cast<ushort4*>(op + d0) = v;
        }
    }
}

}  // namespace

extern "C" void kernel_launch(void* const* d_in, const int* in_sizes, int n_in,
                              void* d_out, int out_size, void* d_ws, size_t ws_size,
                              hipStream_t stream)
{
    const float* x       = (const float*)d_in[0];
    const float* Wqkv    = (const float*)d_in[1];
    const float* Wproj   = (const float*)d_in[2];
    const float* bproj   = (const float*)d_in[3];
    const float* down_w  = (const float*)d_in[4];
    const float* down_b  = (const float*)d_in[5];
    const float* up_w    = (const float*)d_in[6];
    const float* up_b    = (const float*)d_in[7];
    const float* pdown_w = (const float*)d_in[8];
    const float* pdown_b = (const float*)d_in[9];
    const float* pup_w   = (const float*)d_in[10];
    const float* pup_b   = (const float*)d_in[11];
    const int*   task    = (const int*)d_in[12];

    // ws layout (u16 elements). xb and vt share a region (x dead before vt written).
    u16* xb_vt  = (u16*)d_ws;                          //  9,437,184
    u16* wqkvb  = xb_vt  + (size_t)kM * kDim;          //  [3584][1152] (rows 3456+ = pad, never read as output)
    u16* wprjb  = wqkvb  + (size_t)kQS * kDim;         //  1,327,104
    u16* wdownb = wprjb  + (size_t)kDim * kDim;        //  [512][1152]
    u16* wupb   = wdownb + (size_t)512 * kDim;         //  [2304][512]
    u16* h12    = wupb   + (size_t)2304 * 512;         //  [8192][512]
    u16* qkvb   = h12    + (size_t)kM * 512;           //  [8192][3584] padded
    u16* aob    = qkvb   + (size_t)kM * kQS;           //  [8192][1152]
    float* bd   = (float*)(aob + (size_t)kM * kDim);   //  512 f32
    float* bu   = bd + 512;                            //  2304 f32
    float* out  = (float*)d_out;
    u16* xb = xb_vt;
    u16* vt = xb_vt;

    auto cvt = [&](const float* s, u16* d, size_t n) {
        const int n4 = (int)(n / 4);
        cvt_bf16<<<(n4 + 255) / 256, 256, 0, stream>>>(s, d, n4);
    };
    cvt(x,       xb,                  (size_t)kM * kDim);
    cvt(Wqkv,    wqkvb,               (size_t)3 * kDim * kDim);
    cvt(Wproj,   wprjb,               (size_t)kDim * kDim);
    cvt(down_w,  wdownb,              (size_t)kMid * kDim);
    cvt(pdown_w, wdownb + 256 * kDim, (size_t)kMid * kDim);
    {   // up/pup interleaved by K into [2304][512]
        const int n4 = 2304 * 64;
        cvt_bf16_strided<<<(n4 + 255) / 256, 256, 0, stream>>>(up_w,  wupb, n4, 64, 128, 0);
        cvt_bf16_strided<<<(n4 + 255) / 256, 256, 0, stream>>>(pup_w, wupb, n4, 64, 128, 64);
    }
    prep_bias<<<1, 256, 0, stream>>>(down_b, pdown_b, up_b, pup_b, task, bd, bu);

    hipFuncSetAttribute(reinterpret_cast<const void*>(&gemm256<false, false, false>),
                        hipFuncAttributeMaxDynamicSharedMemorySize, 131072);
    hipFuncSetAttribute(reinterpret_cast<const void*>(&gemm256<true, true, true>),
                        hipFuncAttributeMaxDynamicSharedMemorySize, 131072);

    // h12 = tanh(x @ [down_w;pdown_w]^T + bd)
    gemm_mfma<true, false, true, true><<<dim3(kM / 128, 4), 256, 0, stream>>>(
        xb, wdownb, bd, h12, kDim, kDim, kDim, 512, nullptr, 0);
    // qkv = x @ Wqkv^T   (256^2 deep-pipeline; N padded to 3584)
    gemm256<false, false, false><<<dim3(kM / 256, kQS / 256), 512, 131072, stream>>>(
        xb, wqkvb, nullptr, qkvb, kDim, kDim, kDim, kQS, nullptr, 0);
    // qkv[:,1152:3456] += h12 @ wupb^T + bu   [task>=4; K = task>=5 ? 512 : 256]
    gemm256<true, true, true><<<dim3(kM / 256, 9), 512, 131072, stream>>>(
        h12, wupb, bu, qkvb + kDim, 512, 512, 512, kQS, task, 4);

    // vt[(b*9+h)*128+d][tok] = V
    transpose_v<<<dim3(kB * kHeads, kN / 64), 256, 0, stream>>>(qkvb, vt);

    // attention
    attn_mfma<<<dim3(kB * kHeads, kN / 128), 256, 0, stream>>>(qkvb, vt, aob);

    // out = attn_out @ Wproj^T + bproj  (fp32)
    gemm_mfma<false, false, true, false><<<dim3(kM / 128, 9), 256, 0, stream>>>(
        aob, wprjb, bproj, out, kDim, kDim, kDim, kDim, nullptr, 0);

    // second output: down_w passthrough
    hipMemcpyAsync(out + (size_t)kM * kDim, down_w,
                   (size_t)kMid * kDim * sizeof(float),
                   hipMemcpyDeviceToDevice, stream);
}